// Round 9
// baseline (2608.076 us; speedup 1.0000x reference)
//
#include <hip/hip_runtime.h>
#include <cstdint>
#include <cstddef>

#define T_STEPS 512
#define BATCH   64
#define IN_DIM  512
#define HID     768
#define G4H     3072
#define NROWS   32768        // T*B
// h exchange: fp16 plane per batch-group, MFMA-A fragment-linear:
// elem ((ohc>>3)*32 + row)*8 + (ohc&7)  ==  [c8 0..95][row 0..31][j 0..7]
#define HPLANE  49152        // bytes per group plane (768*32 fp16)
#define DBUFB   98304        // bytes per step-slot (2 groups)

typedef __attribute__((ext_vector_type(8))) _Float16 f16x8;
typedef __attribute__((ext_vector_type(4))) float f32x4;

__device__ __forceinline__ float sigmoidf_(float z){ return 1.0f/(1.0f+expf(-z)); }
// fast paths: v_exp_f32 computes 2^x natively; v_rcp_f32 ~1ulp. Tolerance is 2^-8.
__device__ __forceinline__ float sigmoid_fast(float z){
    return __builtin_amdgcn_rcpf(1.0f + __builtin_amdgcn_exp2f(-1.44269504f * z));
}
__device__ __forceinline__ float tanh_fast(float x){
    return 1.0f - 2.0f*__builtin_amdgcn_rcpf(1.0f + __builtin_amdgcn_exp2f(2.88539008f * x));
}
__device__ __forceinline__ unsigned short f16_bits(float v){
    return __builtin_bit_cast(unsigned short, (_Float16)v);
}
__device__ __forceinline__ float h16_to_f(unsigned u){
    return (float)__builtin_bit_cast(_Float16, (unsigned short)(u & 0xffffu));
}

// ---------------- phase 1a: fp32 -> fp16 ----------------
__global__ void cvt_f16_kernel(const float* __restrict__ in, _Float16* __restrict__ out, int n){
    int i = blockIdx.x*256 + threadIdx.x;
    if (i < n) out[i] = (_Float16)in[i];
}

// ---------------- phase 1c: hard-concrete gate s_all[t][h], once ----------------
__global__ void gate_s_kernel(const float* __restrict__ u, const float* __restrict__ la,
                              float* __restrict__ s_all, int n){
    int i = blockIdx.x*256 + threadIdx.x;
    if (i < n){
        int h = i % HID;
        float uu = u[i];
        float lg = (logf(uu) - log1pf(-uu) + la[h]) * 1.5f;
        s_all[i] = fminf(fmaxf(1.2f*sigmoidf_(lg) - 0.1f, 0.f), 1.f);
    }
}

// ---------------- phase 1b: xpT[col][trow] = (x @ W^T)^T, fp16 ----------------
// Panel-major tile order + XCD-affinity swizzle: the 12 blocks sharing one A-panel
// (64 rows of A) are mapped to the SAME XCD (bx%8 round-robin heuristic), so each
// A-panel is fetched into one L2 once. A traffic ~1.5GB -> ~32MB. Output unchanged.
__global__ __launch_bounds__(256, 4) void xproj_gemm_t(
    const _Float16* __restrict__ A, const _Float16* __restrict__ B,
    unsigned short* __restrict__ CT)
{
    const int wave = threadIdx.x >> 6;
    const int lane = threadIdx.x & 63;
    const int bx   = blockIdx.x;           // 6144 blocks
    const int x8   = bx & 7;               // XCD (dispatch round-robin heuristic)
    const int i8   = bx >> 3;              // 0..767
    const int panel = x8 + 8*(i8/12);      // 0..511 = mt (A-panel index)
    const int sub   = i8 % 12;             // block-within-panel
    const int tile  = panel*48 + sub*4 + wave;
    const int mt = tile / 48;
    const int nt = tile % 48;
    const long m0 = (long)mt*64, n0 = (long)nt*64;
    const int lr = lane & 15, lq = lane >> 4;

    f32x4 acc[4][4];
    #pragma unroll
    for (int i=0;i<4;i++)
        #pragma unroll
        for (int j=0;j<4;j++) acc[i][j] = (f32x4){0.f,0.f,0.f,0.f};

    const _Float16* Ap = A + (m0 + lr)*512 + lq*8;
    const _Float16* Bp = B + (n0 + lr)*512 + lq*8;

    for (int k0 = 0; k0 < 512; k0 += 32){
        f16x8 a[4], b[4];
        #pragma unroll
        for (int i=0;i<4;i++) a[i] = *(const f16x8*)(Ap + (long)i*16*512 + k0);
        #pragma unroll
        for (int j=0;j<4;j++) b[j] = *(const f16x8*)(Bp + (long)j*16*512 + k0);
        #pragma unroll
        for (int i=0;i<4;i++)
            #pragma unroll
            for (int j=0;j<4;j++)
                acc[i][j] = __builtin_amdgcn_mfma_f32_16x16x32_f16(a[i], b[j], acc[i][j], 0,0,0);
    }

    #pragma unroll
    for (int i=0;i<4;i++)
        #pragma unroll
        for (int j=0;j<4;j++){
            long col = n0 + 16*j + lr;
            long rb  = m0 + 16*i + lq*4;
            unsigned long long pk =
                  (unsigned long long)f16_bits(acc[i][j][0])
                | ((unsigned long long)f16_bits(acc[i][j][1]) << 16)
                | ((unsigned long long)f16_bits(acc[i][j][2]) << 32)
                | ((unsigned long long)f16_bits(acc[i][j][3]) << 48);
            *(unsigned long long*)(CT + col*NROWS + rb) = pk;
        }
}

// ---------------- phase 2: persistent scan (r8 structure, faster barrier+pointwise) ----------------
// 256 blocks x 512 threads, LDS-pinned 1 block/CU. bg=bx&1: batch half (32 rows);
// cb=bx>>1 owns 6 h-cols (24 gate-cols padded to 32 = 2 N-tiles).
// Waves: ks2=w&1 (12 kb each), mt=(w>>1)&1, nt=(w>>2)&1. 12 MFMAs/wave/step.
// A-fragments load DIRECTLY to VGPRs from the fp16 plane. xpT/s prefetched under
// the barrier wait. Barrier: 16 striped cells/group (8 arrivals each — less RMW
// serialization per MALL line), detection by 16 parallel lanes (slowest cell).
__global__ __launch_bounds__(512, 1) void lstm_scan12(
    const float* __restrict__ U,
    const float* __restrict__ bias,
    const float* __restrict__ s_all,
    const _Float16* __restrict__ xpT,
    float* __restrict__ out,
    char* __restrict__ hbuf,            // 2 slots x 2 groups x 49152 B
    unsigned int* __restrict__ bar)     // 2 grp x 16 cells x 32-dword stride
{
    __shared__ float sRed[2*32*33 + 4]; // K-split partials [ks2][c 0..31][row], stride 33
    __shared__ char  sPad[77824];       // occupancy pin: ~86KB total => 1 block/CU

    const int tid = threadIdx.x;
    const int bx  = blockIdx.x;
    const int bg  = bx & 1;
    const int cb  = bx >> 1;             // 0..127
    const int hc0 = 6*cb;
    const int row0 = 32*bg;

    const int w    = tid >> 6;
    const int lane = tid & 63;
    const int ks2  = w & 1;              // kb in [ks2*12, ks2*12+12)
    const int mt   = (w >> 1) & 1;
    const int nt   = (w >> 2) & 1;
    const int lr   = lane & 15;
    const int kq   = lane >> 4;
    const int mrow = mt*16 + lr;

    if (tid == 0) ((volatile char*)sPad)[0] = 0;   // keep sPad allocated

    // ---- B fragments (U slice) -> VGPRs, fp16, once: 12 x f16x8 ----
    f16x8 Bf[12];
    {
        const int c = nt*16 + lr;            // gate-col within block, 0..31 (>=24 pad)
        #pragma unroll
        for (int i=0;i<12;i++){
            const int kb = ks2*12 + i;
            f16x8 v = {0,0,0,0,0,0,0,0};
            if (c < 24){
                const int g = c/6, jj = c - 6*g;
                const float* up = U + (size_t)(g*HID + hc0 + jj)*HID + kb*32 + kq*8;
                #pragma unroll
                for (int e=0;e<8;e++) v[e] = (_Float16)up[e];
            }
            Bf[i] = v;
        }
    }

    // ---- owner setup: 192 owners (32 rows x 6 cols), one output each ----
    const bool own = tid < 192;
    const int orow = tid & 31;
    const int oj   = tid >> 5;               // 0..5
    const int ohc  = hc0 + (oj < 6 ? oj : 0);
    float c_state = 0.f;
    float b0=0.f,b1=0.f,b2=0.f,b3=0.f;
    float s_cur=0.f, s_nextF=0.f;
    float xvf0=0.f,xvf1=0.f,xvf2=0.f,xvf3=0.f;
    unsigned xr0=0,xr1=0,xr2=0,xr3=0,snr=0;
    const char *xp0=nullptr,*xp1=nullptr,*xp2=nullptr,*xp3=nullptr,*spp=nullptr;
    if (own){
        b0 = bias[ohc]; b1 = bias[HID+ohc]; b2 = bias[2*HID+ohc]; b3 = bias[3*HID+ohc];
        const size_t trow0 = (size_t)row0 + orow;
        xp0 = (const char*)(xpT + (size_t)(0*HID+ohc)*NROWS + trow0);
        xp1 = (const char*)(xpT + (size_t)(1*HID+ohc)*NROWS + trow0);
        xp2 = (const char*)(xpT + (size_t)(2*HID+ohc)*NROWS + trow0);
        xp3 = (const char*)(xpT + (size_t)(3*HID+ohc)*NROWS + trow0);
        spp = (const char*)(s_all + ohc);
        xvf0 = (float)*(const _Float16*)xp0;
        xvf1 = (float)*(const _Float16*)xp1;
        xvf2 = (float)*(const _Float16*)xp2;
        xvf3 = (float)*(const _Float16*)xp3;
        s_cur   = s_all[ohc];
        s_nextF = s_all[HID + ohc];
    }
    __syncthreads();

    for (int t = 0; t < T_STEPS; ++t){
        const char* gsrc = hbuf + (size_t)(t&1)*DBUFB + (size_t)bg*HPLANE;

        // ---- A fragments: 12 direct uncached loads (h(t) guaranteed by barrier) ----
        f32x4 ar[12];
        #pragma unroll
        for (int i=0;i<12;i++){
            const int kb = ks2*12 + i;
            const char* ap = gsrc + (size_t)(((kb*4 + kq)*32 + mrow)*16);
            asm volatile("global_load_dwordx4 %0, %1, off sc0 sc1" : "=v"(ar[i]) : "v"(ap));
        }
        asm volatile("s_waitcnt vmcnt(0)"
            : "+v"(ar[0]),"+v"(ar[1]),"+v"(ar[2]),"+v"(ar[3]),"+v"(ar[4]),"+v"(ar[5]),
              "+v"(ar[6]),"+v"(ar[7]),"+v"(ar[8]),"+v"(ar[9]),"+v"(ar[10]),"+v"(ar[11])
            :: "memory");
        __builtin_amdgcn_sched_barrier(0);

        // ---- 12 MFMAs: 2 chains of 6, summed ----
        f32x4 acA = {0.f,0.f,0.f,0.f};
        f32x4 acB = {0.f,0.f,0.f,0.f};
        #pragma unroll
        for (int i=0;i<6;i++){
            acA = __builtin_amdgcn_mfma_f32_16x16x32_f16(
                      __builtin_bit_cast(f16x8, ar[i]),   Bf[i],   acA, 0,0,0);
            acB = __builtin_amdgcn_mfma_f32_16x16x32_f16(
                      __builtin_bit_cast(f16x8, ar[6+i]), Bf[6+i], acB, 0,0,0);
        }
        f32x4 acc = acA + acB;

        // ---- K-split partial to LDS (vector store, stride 33) ----
        {
            float* rp = sRed + (size_t)(ks2*32 + nt*16 + lr)*33 + mt*16 + kq*4;
            *(f32x4*)rp = acc;
        }
        __syncthreads();

        // ---- pointwise LSTM update (192 owners, 1 value each; fast transcendentals) ----
        if (own){
            if (t){   // consume barrier-prefetched values
                s_cur   = s_nextF;
                s_nextF = __builtin_bit_cast(float, snr);
                xvf0 = h16_to_f(xr0); xvf1 = h16_to_f(xr1);
                xvf2 = h16_to_f(xr2); xvf3 = h16_to_f(xr3);
            }
            const int c0_ = 0*6 + oj, c1_ = 1*6 + oj, c2_ = 2*6 + oj, c3_ = 3*6 + oj;
            float p0 = xvf0 + b0 + sRed[(size_t)c0_*33 + orow] + sRed[(size_t)(32+c0_)*33 + orow];
            float p1 = xvf1 + b1 + sRed[(size_t)c1_*33 + orow] + sRed[(size_t)(32+c1_)*33 + orow];
            float p2 = xvf2 + b2 + sRed[(size_t)c2_*33 + orow] + sRed[(size_t)(32+c2_)*33 + orow];
            float p3 = xvf3 + b3 + sRed[(size_t)c3_*33 + orow] + sRed[(size_t)(32+c3_)*33 + orow];
            const float s = s_cur;
            p0 *= s; p1 *= s; p2 *= s; p3 *= s;
            float ig = sigmoid_fast(p0)*s;
            float fg = sigmoid_fast(p1)*s;
            float cg = tanh_fast(p2)*s;
            float og = sigmoid_fast(p3)*s;
            c_state = fg*c_state + ig*cg;
            float h = og*tanh_fast(c_state);
            out[((size_t)t*BATCH + row0 + orow)*HID + ohc] = h;
            if (t+1 < T_STEPS){
                float hs = h * s_nextF;           // h(t+1 input) pre-scaled by s(t+1)
                unsigned int hv = f16_bits(hs);
                char* dst = hbuf + (size_t)((t+1)&1)*DBUFB + (size_t)bg*HPLANE
                          + 2*(size_t)(((ohc>>3)*32 + orow)*8 + (ohc&7));
                asm volatile("global_store_short %0, %1, off sc0 sc1"
                             :: "v"(dst), "v"(hv) : "memory");
            }
        }

        // ---- barrier: 16 striped cells/group, 16-lane parallel detect ----
        if (t+1 < T_STEPS){
            asm volatile("s_waitcnt vmcnt(0)" ::: "memory");  // h stores at MALL
            __syncthreads();
            // prefetch xv(t+1) + s(t+2) under the barrier wait
            if (own){
                const size_t off = (size_t)(t+1)*BATCH*2;     // bytes: +64 rows/step
                const int ts = (t+2 < T_STEPS) ? (t+2) : (T_STEPS-1);
                const char* sp = spp + (size_t)ts*HID*4;
                asm volatile("global_load_ushort %0, %1, off" : "=v"(xr0) : "v"(xp0 + off));
                asm volatile("global_load_ushort %0, %1, off" : "=v"(xr1) : "v"(xp1 + off));
                asm volatile("global_load_ushort %0, %1, off" : "=v"(xr2) : "v"(xp2 + off));
                asm volatile("global_load_ushort %0, %1, off" : "=v"(xr3) : "v"(xp3 + off));
                asm volatile("global_load_dword %0, %1, off"  : "=v"(snr) : "v"(sp));
            }
            if (tid == 0){
                const unsigned cell = (unsigned)((bg*16 + (cb&15))*32);
                __hip_atomic_fetch_add(bar + cell, 1u, __ATOMIC_RELAXED, __HIP_MEMORY_SCOPE_AGENT);
            }
            if (tid < 16){   // lane k waits for cell k of this group (8 arrivals each)
                const unsigned tgt = (unsigned)(t+1)*8u;
                const unsigned int* cp = bar + (bg*16 + tid)*32;
                while (__hip_atomic_load(cp, __ATOMIC_RELAXED, __HIP_MEMORY_SCOPE_AGENT) < tgt)
                    __builtin_amdgcn_s_sleep(1);
            }
            __syncthreads();
        }
    }
}

extern "C" void kernel_launch(void* const* d_in, const int* in_sizes, int n_in,
                              void* d_out, int out_size, void* d_ws, size_t ws_size,
                              hipStream_t stream){
    const float* x  = (const float*)d_in[0];
    const float* W  = (const float*)d_in[1];
    const float* U  = (const float*)d_in[2];
    const float* b  = (const float*)d_in[3];
    const float* la = (const float*)d_in[4];
    const float* u  = (const float*)d_in[5];
    float* out = (float*)d_out;

    char* ws = (char*)d_ws;
    char*           hbuf  = ws;                                       // 196608 B (2 slots)
    unsigned int*   bar   = (unsigned int*)(ws + 196608);             // 4096 B (32 cells x 128B)
    _Float16*       xf16  = (_Float16*)(ws + 200704);                 // 33554432 B
    float*          s_all = (float*)(ws + 200704);                    // 1572864 B, aliases xf16
    _Float16*       wf16  = (_Float16*)(ws + 200704 + 33554432);      // 3145728 B
    unsigned short* xpT   = (unsigned short*)(ws + 36900864);         // 201326592 B
    // total 238227456 B <= proven footprint. s_all aliases xf16: xf16 is dead
    // after xproj_gemm_t; gate_s_kernel runs after it on the same stream.

    hipMemsetAsync(d_ws, 0, 200704, stream);   // zero hbuf (h0=0) + barrier

    cvt_f16_kernel<<<65536, 256, 0, stream>>>(x, xf16, NROWS*IN_DIM);
    cvt_f16_kernel<<<6144,  256, 0, stream>>>(W, wf16, G4H*IN_DIM);
    xproj_gemm_t<<<6144, 256, 0, stream>>>(xf16, wf16, xpT);
    gate_s_kernel<<<1536, 256, 0, stream>>>(u, la, s_all, T_STEPS*HID);
    lstm_scan12<<<256, 512, 0, stream>>>(U, b, s_all, (const _Float16*)xpT, out, hbuf, bar);
}